// Round 1
// baseline (42673.126 us; speedup 1.0000x reference)
//
#include <hip/hip_runtime.h>
#include <math.h>

#define N_TOK   262144
#define DIMV    128
#define KCODE   1024
#define LEV     3
#define LPT     4              // lanes per token
#define DPL     32             // dims per lane (DIMV / LPT)
#define BLOCK   256
#define TPB     (BLOCK / LPT)  // 64 tokens per block

// ws layout (doubles):
//   ws[0]            : global loss accumulator (sum over levels/tokens/dims of (z_q - r)^2)
//   ws[8 .. 8+3072)  : ee64[l*1024 + c] = ||E[l][c]||^2 in fp64 (offset 64 bytes, aligned)

__global__ void rvq_prep(const float* __restrict__ cb, double* __restrict__ ws) {
    int c = blockIdx.x * blockDim.x + threadIdx.x;
    if (c == 0) ws[0] = 0.0;
    if (c < LEV * KCODE) {
        const float* e = cb + (size_t)c * DIMV;
        double s = 0.0;
        #pragma unroll 8
        for (int j = 0; j < DIMV; ++j) {
            double v = (double)e[j];
            s = fma(v, v, s);
        }
        ws[8 + c] = s;
    }
}

__global__ __launch_bounds__(BLOCK) void rvq_main(const float* __restrict__ ze,
                                                  const float* __restrict__ cb,
                                                  float* __restrict__ out,
                                                  double* __restrict__ ws) {
    const double* __restrict__ ee = ws + 8;
    const int lane_q = threadIdx.x & (LPT - 1);
    const long t = (long)blockIdx.x * TPB + (threadIdx.x >> 2);

    const float* zptr = ze + (size_t)t * DIMV + lane_q * DPL;

    // residual in fp64, this lane's 32 dims
    double r[DPL];
    #pragma unroll
    for (int j = 0; j < DPL; j += 4) {
        float4 v = *(const float4*)(zptr + j);
        r[j + 0] = (double)v.x;
        r[j + 1] = (double)v.y;
        r[j + 2] = (double)v.z;
        r[j + 3] = (double)v.w;
    }

    float* out_idx = out + (size_t)N_TOK * DIMV + 2;
    double loss = 0.0;

    for (int l = 0; l < LEV; ++l) {
        // ||r||^2 (identical on all 4 lanes of the token group via butterfly)
        double rr = 0.0;
        #pragma unroll
        for (int j = 0; j < DPL; ++j) rr = fma(r[j], r[j], rr);
        rr += __shfl_xor(rr, 1);
        rr += __shfl_xor(rr, 2);

        const float* cbl = cb + (size_t)l * KCODE * DIMV + lane_q * DPL;
        const double* eel = ee + l * KCODE;

        double best = 1.0e300;
        int bestc = 0;

        for (int c = 0; c < KCODE; ++c) {
            const float4* ep = (const float4*)(cbl + (size_t)c * DIMV);
            double a0 = 0.0, a1 = 0.0, a2 = 0.0, a3 = 0.0;
            #pragma unroll
            for (int u = 0; u < 8; ++u) {
                float4 a = ep[u];
                a0 = fma(r[4 * u + 0], (double)a.x, a0);
                a1 = fma(r[4 * u + 1], (double)a.y, a1);
                a2 = fma(r[4 * u + 2], (double)a.z, a2);
                a3 = fma(r[4 * u + 3], (double)a.w, a3);
            }
            double dot = (a0 + a1) + (a2 + a3);
            dot += __shfl_xor(dot, 1);
            dot += __shfl_xor(dot, 2);

            double d = rr + eel[c] - 2.0 * dot;
            if (d < best) { best = d; bestc = c; }  // strict < => first-index tie-break
        }

        // gather winning code, accumulate loss, update residual (faithful to ref ops)
        const float4* eb = (const float4*)(cbl + (size_t)bestc * DIMV);
        #pragma unroll
        for (int u = 0; u < 8; ++u) {
            float4 a = eb[u];
            {
                double zq = (double)a.x, rv = r[4 * u + 0];
                double t1 = zq - rv;              // (z_q - residual)
                loss = fma(t1, t1, loss);
                double zqst = rv + t1;            // straight-through value
                r[4 * u + 0] = rv - zqst;         // residual update
            }
            {
                double zq = (double)a.y, rv = r[4 * u + 1];
                double t1 = zq - rv;
                loss = fma(t1, t1, loss);
                double zqst = rv + t1;
                r[4 * u + 1] = rv - zqst;
            }
            {
                double zq = (double)a.z, rv = r[4 * u + 2];
                double t1 = zq - rv;
                loss = fma(t1, t1, loss);
                double zqst = rv + t1;
                r[4 * u + 2] = rv - zqst;
            }
            {
                double zq = (double)a.w, rv = r[4 * u + 3];
                double t1 = zq - rv;
                loss = fma(t1, t1, loss);
                double zqst = rv + t1;
                r[4 * u + 3] = rv - zqst;
            }
        }

        if (lane_q == 0) out_idx[t * 3 + l] = (float)bestc;
    }

    // z_q_total = z_e - residual_final  (exact up to fp64 rounding)
    {
        float* optr = out + (size_t)t * DIMV + lane_q * DPL;
        #pragma unroll
        for (int j = 0; j < DPL; j += 4) {
            float4 v = *(const float4*)(zptr + j);
            float4 o;
            o.x = (float)((double)v.x - r[j + 0]);
            o.y = (float)((double)v.y - r[j + 1]);
            o.z = (float)((double)v.z - r[j + 2]);
            o.w = (float)((double)v.w - r[j + 3]);
            *(float4*)(optr + j) = o;
        }
    }

    // block-level loss reduction -> one double atomic per block
    loss += __shfl_xor(loss, 1);
    loss += __shfl_xor(loss, 2);
    loss += __shfl_xor(loss, 4);
    loss += __shfl_xor(loss, 8);
    loss += __shfl_xor(loss, 16);
    loss += __shfl_xor(loss, 32);

    __shared__ double ssum[BLOCK / 64];
    int wave = threadIdx.x >> 6;
    if ((threadIdx.x & 63) == 0) ssum[wave] = loss;
    __syncthreads();
    if (threadIdx.x == 0) {
        double s = 0.0;
        #pragma unroll
        for (int w = 0; w < BLOCK / 64; ++w) s += ssum[w];
        atomicAdd(ws, s);
    }
}

__global__ void rvq_fin(const double* __restrict__ ws, float* __restrict__ out) {
    double vq = ws[0] / ((double)N_TOK * (double)DIMV * (double)LEV);
    out[(size_t)N_TOK * DIMV + 0] = (float)vq;
    out[(size_t)N_TOK * DIMV + 1] = (float)(0.25 * vq);
}

extern "C" void kernel_launch(void* const* d_in, const int* in_sizes, int n_in,
                              void* d_out, int out_size, void* d_ws, size_t ws_size,
                              hipStream_t stream) {
    const float* ze = (const float*)d_in[0];
    const float* cb = (const float*)d_in[1];
    float* out = (float*)d_out;
    double* ws = (double*)d_ws;

    rvq_prep<<<(LEV * KCODE + 255) / 256, 256, 0, stream>>>(cb, ws);
    rvq_main<<<N_TOK / TPB, BLOCK, 0, stream>>>(ze, cb, out, ws);
    rvq_fin<<<1, 1, 0, stream>>>(ws, out);
}

// Round 2
// 5127.640 us; speedup vs baseline: 8.3222x; 8.3222x over previous
//
#include <hip/hip_runtime.h>
#include <math.h>

#define N_TOK   262144
#define DIMV    128
#define KCODE   1024
#define LEV     3
#define LPT     8              // lanes per token
#define DPL     16             // dims per lane
#define BLOCK   256
#define TPB     (BLOCK / LPT)  // 32 tokens per block
#define TILE    64             // codes per LDS tile
#define CSTR    640            // LDS bytes per code (8 slices * 80)
#define SSTR    80             // LDS bytes per 16-dim slice (64 data + 16 pad -> bank-spread)
#define EPS     2.0e-3f        // fp32 distance error band (worst-case err ~3e-4, 7x margin)

// ws layout:
//   double ws[0]           : global loss accumulator
//   double ws[8..3080)     : ee64[l*1024+c] = ||E||^2 fp64
//   float  wsf[0..3072)    : ee32 copies, at (float*)(ws+3080)

__global__ void rvq_prep(const float* __restrict__ cb, double* __restrict__ ws) {
    int c = blockIdx.x * blockDim.x + threadIdx.x;
    if (c == 0) ws[0] = 0.0;
    if (c < LEV * KCODE) {
        const float* e = cb + (size_t)c * DIMV;
        double s = 0.0;
        #pragma unroll 8
        for (int j = 0; j < DIMV; ++j) {
            double v = (double)e[j];
            s = fma(v, v, s);
        }
        ws[8 + c] = s;
        float* wsf = (float*)(ws + 8 + LEV * KCODE);
        wsf[c] = (float)s;
    }
}

__global__ __launch_bounds__(BLOCK) void rvq_main(const float* __restrict__ ze,
                                                  const float* __restrict__ cb,
                                                  float* __restrict__ out,
                                                  double* __restrict__ ws) {
    __shared__ __align__(16) unsigned char tileb[TILE * CSTR]; // 40 KB
    __shared__ __align__(16) float ee32s[KCODE];               // 4 KB
    __shared__ double ssum[BLOCK / 64];

    const double* __restrict__ ee64 = ws + 8;
    const float* __restrict__ wsf = (const float*)(ws + 8 + LEV * KCODE);

    const int tid = threadIdx.x;
    const int lane_q = tid & (LPT - 1);
    const int gl = (tid & 63) & ~(LPT - 1);   // wave-lane base of this token's 8-lane group
    const long t = (long)blockIdx.x * TPB + (tid >> 3);

    const float* zptr = ze + (size_t)t * DIMV + lane_q * DPL;

    double r64[DPL];
    float4 r4[4];
    #pragma unroll
    for (int u = 0; u < 4; ++u) {
        float4 v = ((const float4*)zptr)[u];
        r4[u] = v;
        r64[4 * u + 0] = (double)v.x;
        r64[4 * u + 1] = (double)v.y;
        r64[4 * u + 2] = (double)v.z;
        r64[4 * u + 3] = (double)v.w;
    }

    float* out_idx = out + (size_t)N_TOK * DIMV + 2;
    double loss = 0.0;

    for (int l = 0; l < LEV; ++l) {
        float best = 3.0e38f;
        int pos = 0;
        float cd[4] = {3.0e38f, 3.0e38f, 3.0e38f, 3.0e38f};
        int   ci[4] = {0, 0, 0, 0};

        for (int tile = 0; tile < KCODE / TILE; ++tile) {
            __syncthreads();   // previous tile / previous-level LDS reads complete
            if (tile == 0) {
                ((float4*)ee32s)[tid] = ((const float4*)(wsf + l * KCODE))[tid];
            }
            {
                const float4* src4 = (const float4*)(cb + ((size_t)l * KCODE + tile * TILE) * DIMV);
                #pragma unroll
                for (int i = 0; i < 8; ++i) {
                    int idx = i * BLOCK + tid;       // 0..2047
                    int cl = idx >> 5;               // code 0..63
                    int d4 = idx & 31;               // float4 within code
                    float4 v = src4[cl * 32 + d4];
                    *(float4*)(tileb + cl * CSTR + (d4 >> 2) * SSTR + (d4 & 3) * 16) = v;
                }
            }
            __syncthreads();

            #pragma unroll
            for (int g = 0; g < 8; ++g) {
                float v[8];
                #pragma unroll
                for (int j = 0; j < 8; ++j) {
                    const unsigned char* p = tileb + (g * 8 + j) * CSTR + lane_q * SSTR;
                    float4 a0 = *(const float4*)(p);
                    float4 a1 = *(const float4*)(p + 16);
                    float4 a2 = *(const float4*)(p + 32);
                    float4 a3 = *(const float4*)(p + 48);
                    float s = 0.0f;
                    s = fmaf(a0.x, r4[0].x, s); s = fmaf(a0.y, r4[0].y, s);
                    s = fmaf(a0.z, r4[0].z, s); s = fmaf(a0.w, r4[0].w, s);
                    s = fmaf(a1.x, r4[1].x, s); s = fmaf(a1.y, r4[1].y, s);
                    s = fmaf(a1.z, r4[1].z, s); s = fmaf(a1.w, r4[1].w, s);
                    s = fmaf(a2.x, r4[2].x, s); s = fmaf(a2.y, r4[2].y, s);
                    s = fmaf(a2.z, r4[2].z, s); s = fmaf(a2.w, r4[2].w, s);
                    s = fmaf(a3.x, r4[3].x, s); s = fmaf(a3.y, r4[3].y, s);
                    s = fmaf(a3.z, r4[3].z, s); s = fmaf(a3.w, r4[3].w, s);
                    v[j] = s;
                }
                bool hi4 = (lane_q & 4) != 0;
                float w0, w1, w2, w3;
                {
                    float sd, rc;
                    sd = hi4 ? v[0] : v[4]; rc = __shfl_xor(sd, 4); w0 = (hi4 ? v[4] : v[0]) + rc;
                    sd = hi4 ? v[1] : v[5]; rc = __shfl_xor(sd, 4); w1 = (hi4 ? v[5] : v[1]) + rc;
                    sd = hi4 ? v[2] : v[6]; rc = __shfl_xor(sd, 4); w2 = (hi4 ? v[6] : v[2]) + rc;
                    sd = hi4 ? v[3] : v[7]; rc = __shfl_xor(sd, 4); w3 = (hi4 ? v[7] : v[3]) + rc;
                }
                bool hi2 = (lane_q & 2) != 0;
                float x0, x1;
                {
                    float sd, rc;
                    sd = hi2 ? w0 : w2; rc = __shfl_xor(sd, 2); x0 = (hi2 ? w2 : w0) + rc;
                    sd = hi2 ? w1 : w3; rc = __shfl_xor(sd, 2); x1 = (hi2 ? w3 : w1) + rc;
                }
                bool hi1 = (lane_q & 1) != 0;
                float dot;
                {
                    float sd = hi1 ? x0 : x1;
                    float rc = __shfl_xor(sd, 1);
                    dot = (hi1 ? x1 : x0) + rc;
                }

                int code = tile * TILE + g * 8 + lane_q;
                float d = fmaf(-2.0f, dot, ee32s[code]);
                bool q = d < best + EPS;
                if (q) {
                    int sel = pos & 3;
                    cd[0] = (sel == 0) ? d : cd[0]; ci[0] = (sel == 0) ? code : ci[0];
                    cd[1] = (sel == 1) ? d : cd[1]; ci[1] = (sel == 1) ? code : ci[1];
                    cd[2] = (sel == 2) ? d : cd[2]; ci[2] = (sel == 2) ? code : ci[2];
                    cd[3] = (sel == 3) ? d : cd[3]; ci[3] = (sel == 3) ? code : ci[3];
                    pos++;
                }
                best = fminf(best, d);
            }
        }

        float gb = best;
        gb = fminf(gb, __shfl_xor(gb, 1));
        gb = fminf(gb, __shfl_xor(gb, 2));
        gb = fminf(gb, __shfl_xor(gb, 4));
        float cut = gb + EPS;

        double bd = 1.0e300;
        int bc = KCODE;
        #pragma unroll
        for (int sl = 0; sl < 8; ++sl) {
            int pcnt = __shfl(pos, gl + sl);
            pcnt = pcnt > 4 ? 4 : pcnt;
            #pragma unroll
            for (int k = 0; k < 4; ++k) {
                float dd = __shfl(cd[k], gl + sl);
                int cc = __shfl(ci[k], gl + sl);
                if (k < pcnt && dd <= cut) {   // group-uniform predicate
                    const float4* ep = (const float4*)(cb + ((size_t)l * KCODE + cc) * DIMV + lane_q * DPL);
                    double s = 0.0;
                    #pragma unroll
                    for (int u = 0; u < 4; ++u) {
                        float4 a = ep[u];
                        s = fma((double)a.x, r64[4 * u + 0], s);
                        s = fma((double)a.y, r64[4 * u + 1], s);
                        s = fma((double)a.z, r64[4 * u + 2], s);
                        s = fma((double)a.w, r64[4 * u + 3], s);
                    }
                    s += __shfl_xor(s, 1);
                    s += __shfl_xor(s, 2);
                    s += __shfl_xor(s, 4);
                    double dd64 = ee64[l * KCODE + cc] - 2.0 * s;
                    if (dd64 < bd || (dd64 == bd && cc < bc)) { bd = dd64; bc = cc; }
                }
            }
        }

        {
            const float4* eb = (const float4*)(cb + ((size_t)l * KCODE + bc) * DIMV + lane_q * DPL);
            #pragma unroll
            for (int u = 0; u < 4; ++u) {
                float4 a = eb[u];
                {
                    double zq = (double)a.x, rv = r64[4 * u + 0];
                    double t1 = zq - rv; loss = fma(t1, t1, loss);
                    double zqst = rv + t1; r64[4 * u + 0] = rv - zqst;
                }
                {
                    double zq = (double)a.y, rv = r64[4 * u + 1];
                    double t1 = zq - rv; loss = fma(t1, t1, loss);
                    double zqst = rv + t1; r64[4 * u + 1] = rv - zqst;
                }
                {
                    double zq = (double)a.z, rv = r64[4 * u + 2];
                    double t1 = zq - rv; loss = fma(t1, t1, loss);
                    double zqst = rv + t1; r64[4 * u + 2] = rv - zqst;
                }
                {
                    double zq = (double)a.w, rv = r64[4 * u + 3];
                    double t1 = zq - rv; loss = fma(t1, t1, loss);
                    double zqst = rv + t1; r64[4 * u + 3] = rv - zqst;
                }
                r4[u] = make_float4((float)r64[4 * u + 0], (float)r64[4 * u + 1],
                                    (float)r64[4 * u + 2], (float)r64[4 * u + 3]);
            }
        }
        if (lane_q == 0) out_idx[t * 3 + l] = (float)bc;
    }

    {
        float* optr = out + (size_t)t * DIMV + lane_q * DPL;
        #pragma unroll
        for (int u = 0; u < 4; ++u) {
            float4 vz = ((const float4*)zptr)[u];
            float4 o;
            o.x = (float)((double)vz.x - r64[4 * u + 0]);
            o.y = (float)((double)vz.y - r64[4 * u + 1]);
            o.z = (float)((double)vz.z - r64[4 * u + 2]);
            o.w = (float)((double)vz.w - r64[4 * u + 3]);
            ((float4*)optr)[u] = o;
        }
    }

    loss += __shfl_xor(loss, 1);
    loss += __shfl_xor(loss, 2);
    loss += __shfl_xor(loss, 4);
    loss += __shfl_xor(loss, 8);
    loss += __shfl_xor(loss, 16);
    loss += __shfl_xor(loss, 32);
    int wave = tid >> 6;
    if ((tid & 63) == 0) ssum[wave] = loss;
    __syncthreads();
    if (tid == 0) {
        double s = 0.0;
        #pragma unroll
        for (int w = 0; w < BLOCK / 64; ++w) s += ssum[w];
        atomicAdd(ws, s);
    }
}

__global__ void rvq_fin(const double* __restrict__ ws, float* __restrict__ out) {
    double vq = ws[0] / ((double)N_TOK * (double)DIMV * (double)LEV);
    out[(size_t)N_TOK * DIMV + 0] = (float)vq;
    out[(size_t)N_TOK * DIMV + 1] = (float)(0.25 * vq);
}

extern "C" void kernel_launch(void* const* d_in, const int* in_sizes, int n_in,
                              void* d_out, int out_size, void* d_ws, size_t ws_size,
                              hipStream_t stream) {
    const float* ze = (const float*)d_in[0];
    const float* cb = (const float*)d_in[1];
    float* out = (float*)d_out;
    double* ws = (double*)d_ws;

    rvq_prep<<<(LEV * KCODE + 255) / 256, 256, 0, stream>>>(cb, ws);
    rvq_main<<<N_TOK / TPB, BLOCK, 0, stream>>>(ze, cb, out, ws);
    rvq_fin<<<1, 1, 0, stream>>>(ws, out);
}

// Round 3
// 833.025 us; speedup vs baseline: 51.2267x; 6.1554x over previous
//
#include <hip/hip_runtime.h>
#include <math.h>

#define N_TOK   262144
#define DIMV    128
#define KCODE   1024
#define LEV     3
#define BLOCK   256
#define NTILES  64          // 16-code tiles per level
#define EPS     0.08f       // fp16 2-product distance error band (~40 sigma)

typedef _Float16 f16x8 __attribute__((ext_vector_type(8)));
typedef float f32x4 __attribute__((ext_vector_type(4)));

// ws layout: double ws[0] = loss accum; double ee64[3072] @ ws+8;
//            float ee32b[3072] (= float(ee64 + 8192)) @ (float*)(ws + 8 + 3072)

__global__ void rvq_prep(const float* __restrict__ cb, double* __restrict__ ws) {
    int c = blockIdx.x * blockDim.x + threadIdx.x;
    if (c == 0) ws[0] = 0.0;
    if (c < LEV * KCODE) {
        const float* e = cb + (size_t)c * DIMV;
        double s = 0.0;
        #pragma unroll 8
        for (int j = 0; j < DIMV; ++j) { double v = (double)e[j]; s = fma(v, v, s); }
        ws[8 + c] = s;
        ((float*)(ws + 8 + LEV * KCODE))[c] = (float)(s + 8192.0);
    }
}

__device__ inline void stage_write(unsigned char* dst, int tid, float4 g0, float4 g1) {
    f16x8 v;
    v[0]=(_Float16)g0.x; v[1]=(_Float16)g0.y; v[2]=(_Float16)g0.z; v[3]=(_Float16)g0.w;
    v[4]=(_Float16)g1.x; v[5]=(_Float16)g1.y; v[6]=(_Float16)g1.z; v[7]=(_Float16)g1.w;
    // chunk (ks = tid[3:2], lidx = (tid&3)*16 + (tid>>4)) -> lane-addressable B-frag layout
    *(f16x8*)(dst + ((((tid>>2)&3)*64) + ((tid&3)*16 + (tid>>4))) * 16) = v;
}

__device__ inline unsigned sel4(const unsigned v[4], int j) {
    unsigned a = (j & 1) ? v[1] : v[0];
    unsigned b = (j & 1) ? v[3] : v[2];
    return (j & 2) ? b : a;
}

__global__ __launch_bounds__(BLOCK, 2) void rvq_main(const float* __restrict__ ze,
                                                     const float* __restrict__ cb,
                                                     float* __restrict__ out,
                                                     double* __restrict__ ws) {
    __shared__ __align__(16) unsigned char Bbuf[2][4096];
    __shared__ __align__(16) float eeS[KCODE];
    __shared__ double ssum[4];

    const double* __restrict__ ee64g = ws + 8;
    const float*  __restrict__ eebg  = (const float*)(ws + 8 + LEV * KCODE);

    const int tid  = threadIdx.x;
    const int lane = tid & 63;
    const int wid  = tid >> 6;
    const int q    = lane >> 4;   // quad: owns dims st*32 + q*8 + j
    const int col  = lane & 15;   // A-operand row (token), B-operand col (code)
    const long tokbase = (long)blockIdx.x * 128 + wid * 32;

    float r[2][4][8];             // residual, fp32, reference-exact op chain
    f16x8 Ah[2][4], Al[2][4];     // A-frags: hi/lo fp16 split, per Mtile per kstep

    #pragma unroll
    for (int mt = 0; mt < 2; ++mt) {
        const float4* zp = (const float4*)(ze + (size_t)(tokbase + mt*16 + col) * DIMV);
        #pragma unroll
        for (int st = 0; st < 4; ++st) {
            float4 a = zp[st*8 + q*2], b = zp[st*8 + q*2 + 1];
            r[mt][st][0]=a.x; r[mt][st][1]=a.y; r[mt][st][2]=a.z; r[mt][st][3]=a.w;
            r[mt][st][4]=b.x; r[mt][st][5]=b.y; r[mt][st][6]=b.z; r[mt][st][7]=b.w;
        }
    }
    #pragma unroll
    for (int mt = 0; mt < 2; ++mt)
        #pragma unroll
        for (int st = 0; st < 4; ++st) {
            f16x8 h, lo;
            #pragma unroll
            for (int j = 0; j < 8; ++j) {
                float x = r[mt][st][j];
                _Float16 hh = (_Float16)x;
                h[j] = hh;
                lo[j] = (_Float16)(x - (float)hh);
            }
            Ah[mt][st] = h; Al[mt][st] = lo;
        }

    double loss = 0.0;
    float* out_idx = out + (size_t)N_TOK * DIMV + 2;

    for (int l = 0; l < LEV; ++l) {
        __syncthreads();   // prior level's LDS users done
        ((float4*)eeS)[tid] = ((const float4*)(eebg + (size_t)l * KCODE))[tid];
        float4 g0, g1;
        {   // stage tile 0
            const float4* p = (const float4*)(cb + ((size_t)l*KCODE + (tid>>4)) * DIMV + (tid&15)*8);
            g0 = p[0]; g1 = p[1];
            stage_write(Bbuf[0], tid, g0, g1);
        }
        __syncthreads();

        unsigned m1[2][4], m2[2][4];
        #pragma unroll
        for (int mt = 0; mt < 2; ++mt)
            #pragma unroll
            for (int i = 0; i < 4; ++i) { m1[mt][i] = 0xFFFFFFFFu; m2[mt][i] = 0xFFFFFFFFu; }

        for (int t = 0; t < NTILES; ++t) {
            if (t < NTILES - 1) {
                const float4* p = (const float4*)(cb + ((size_t)l*KCODE + (t+1)*16 + (tid>>4)) * DIMV + (tid&15)*8);
                g0 = p[0]; g1 = p[1];
            }
            {
                const unsigned char* bb = Bbuf[t & 1];
                f16x8 B0 = *(const f16x8*)(bb + (0*64 + lane)*16);
                f16x8 B1 = *(const f16x8*)(bb + (1*64 + lane)*16);
                f16x8 B2 = *(const f16x8*)(bb + (2*64 + lane)*16);
                f16x8 B3 = *(const f16x8*)(bb + (3*64 + lane)*16);
                float eeq = eeS[t*16 + col];
                f32x4 c0 = {0.f,0.f,0.f,0.f}, c1v = {0.f,0.f,0.f,0.f};
                c0  = __builtin_amdgcn_mfma_f32_16x16x32_f16(Ah[0][0], B0, c0, 0,0,0);
                c0  = __builtin_amdgcn_mfma_f32_16x16x32_f16(Al[0][0], B0, c0, 0,0,0);
                c1v = __builtin_amdgcn_mfma_f32_16x16x32_f16(Ah[1][0], B0, c1v, 0,0,0);
                c1v = __builtin_amdgcn_mfma_f32_16x16x32_f16(Al[1][0], B0, c1v, 0,0,0);
                c0  = __builtin_amdgcn_mfma_f32_16x16x32_f16(Ah[0][1], B1, c0, 0,0,0);
                c0  = __builtin_amdgcn_mfma_f32_16x16x32_f16(Al[0][1], B1, c0, 0,0,0);
                c1v = __builtin_amdgcn_mfma_f32_16x16x32_f16(Ah[1][1], B1, c1v, 0,0,0);
                c1v = __builtin_amdgcn_mfma_f32_16x16x32_f16(Al[1][1], B1, c1v, 0,0,0);
                c0  = __builtin_amdgcn_mfma_f32_16x16x32_f16(Ah[0][2], B2, c0, 0,0,0);
                c0  = __builtin_amdgcn_mfma_f32_16x16x32_f16(Al[0][2], B2, c0, 0,0,0);
                c1v = __builtin_amdgcn_mfma_f32_16x16x32_f16(Ah[1][2], B2, c1v, 0,0,0);
                c1v = __builtin_amdgcn_mfma_f32_16x16x32_f16(Al[1][2], B2, c1v, 0,0,0);
                c0  = __builtin_amdgcn_mfma_f32_16x16x32_f16(Ah[0][3], B3, c0, 0,0,0);
                c0  = __builtin_amdgcn_mfma_f32_16x16x32_f16(Al[0][3], B3, c0, 0,0,0);
                c1v = __builtin_amdgcn_mfma_f32_16x16x32_f16(Ah[1][3], B3, c1v, 0,0,0);
                c1v = __builtin_amdgcn_mfma_f32_16x16x32_f16(Al[1][3], B3, c1v, 0,0,0);
                #pragma unroll
                for (int i = 0; i < 4; ++i) {
                    unsigned k0 = (__float_as_uint(fmaf(-2.0f, c0[i],  eeq)) << 6) | (unsigned)t;
                    m2[0][i] = min(m2[0][i], max(m1[0][i], k0));
                    m1[0][i] = min(m1[0][i], k0);
                    unsigned k1_ = (__float_as_uint(fmaf(-2.0f, c1v[i], eeq)) << 6) | (unsigned)t;
                    m2[1][i] = min(m2[1][i], max(m1[1][i], k1_));
                    m1[1][i] = min(m1[1][i], k1_);
                }
            }
            if (t < NTILES - 1) stage_write(Bbuf[(t+1)&1], tid, g0, g1);
            __syncthreads();
        }

        // ---- phase 2: cross-lane top-2 reduce (with lane-col meta), select, rescore, update ----
        unsigned k1[2][4], k2[2][4], q1[2][4], q2[2][4];
        #pragma unroll
        for (int mt = 0; mt < 2; ++mt)
            #pragma unroll
            for (int i = 0; i < 4; ++i) {
                k1[mt][i] = m1[mt][i]; k2[mt][i] = m2[mt][i];
                q1[mt][i] = (unsigned)col; q2[mt][i] = (unsigned)col;
            }
        #pragma unroll
        for (int d = 1; d <= 8; d <<= 1) {
            #pragma unroll
            for (int mt = 0; mt < 2; ++mt)
                #pragma unroll
                for (int i = 0; i < 4; ++i) {
                    unsigned ok1 = __shfl_xor(k1[mt][i], d), oq1 = __shfl_xor(q1[mt][i], d);
                    unsigned ok2 = __shfl_xor(k2[mt][i], d), oq2 = __shfl_xor(q2[mt][i], d);
                    bool sw = (ok1 < k1[mt][i]) || (ok1 == k1[mt][i] && oq1 < q1[mt][i]);
                    unsigned n1 = sw ? ok1 : k1[mt][i], nq1 = sw ? oq1 : q1[mt][i];
                    unsigned hk = sw ? k1[mt][i] : ok1, hq = sw ? q1[mt][i] : oq1;
                    bool s2 = (ok2 < k2[mt][i]) || (ok2 == k2[mt][i] && oq2 < q2[mt][i]);
                    unsigned p2 = s2 ? ok2 : k2[mt][i], pq = s2 ? oq2 : q2[mt][i];
                    bool s3 = (p2 < hk) || (p2 == hk && pq < hq);
                    k1[mt][i] = n1;              q1[mt][i] = nq1;
                    k2[mt][i] = s3 ? p2 : hk;    q2[mt][i] = s3 ? pq : hq;
                }
        }

        int jsel = (lane >> 2) & 3;
        int S = ((col >> 2) << 4) | ((col & 3) << 2);   // source lane holding token col's keys

        #pragma unroll
        for (int mt = 0; mt < 2; ++mt) {
            unsigned sk1 = sel4(k1[mt], jsel), sq1 = sel4(q1[mt], jsel);
            unsigned sk2 = sel4(k2[mt], jsel), sq2 = sel4(q2[mt], jsel);
            unsigned bk1 = (unsigned)__shfl((int)sk1, S);
            unsigned bq1 = (unsigned)__shfl((int)sq1, S);
            unsigned bk2 = (unsigned)__shfl((int)sk2, S);
            unsigned bq2 = (unsigned)__shfl((int)sq2, S);
            int c1c = (int)(((bk1 & 63u) << 4) | bq1);
            int c2c = (int)(((bk2 & 63u) << 4) | bq2);
            float d1 = __uint_as_float((bk1 >> 6) | 0x44000000u) - 8192.0f;
            float d2 = __uint_as_float((bk2 >> 6) | 0x44000000u) - 8192.0f;
            int bc = c1c;
            if (d2 - d1 < EPS) {   // ambiguous: exact fp64 rescore of both (uniform per token group)
                double s1 = 0.0, s2d = 0.0;
                const float4* e1 = (const float4*)(cb + ((size_t)l*KCODE + c1c)*DIMV);
                const float4* e2 = (const float4*)(cb + ((size_t)l*KCODE + c2c)*DIMV);
                #pragma unroll
                for (int st = 0; st < 4; ++st) {
                    float4 a = e1[st*8 + q*2], b = e1[st*8 + q*2 + 1];
                    s1 = fma((double)a.x,(double)r[mt][st][0],s1); s1 = fma((double)a.y,(double)r[mt][st][1],s1);
                    s1 = fma((double)a.z,(double)r[mt][st][2],s1); s1 = fma((double)a.w,(double)r[mt][st][3],s1);
                    s1 = fma((double)b.x,(double)r[mt][st][4],s1); s1 = fma((double)b.y,(double)r[mt][st][5],s1);
                    s1 = fma((double)b.z,(double)r[mt][st][6],s1); s1 = fma((double)b.w,(double)r[mt][st][7],s1);
                    float4 a2 = e2[st*8 + q*2], b2 = e2[st*8 + q*2 + 1];
                    s2d = fma((double)a2.x,(double)r[mt][st][0],s2d); s2d = fma((double)a2.y,(double)r[mt][st][1],s2d);
                    s2d = fma((double)a2.z,(double)r[mt][st][2],s2d); s2d = fma((double)a2.w,(double)r[mt][st][3],s2d);
                    s2d = fma((double)b2.x,(double)r[mt][st][4],s2d); s2d = fma((double)b2.y,(double)r[mt][st][5],s2d);
                    s2d = fma((double)b2.z,(double)r[mt][st][6],s2d); s2d = fma((double)b2.w,(double)r[mt][st][7],s2d);
                }
                s1  += __shfl_xor(s1, 16);  s1  += __shfl_xor(s1, 32);
                s2d += __shfl_xor(s2d, 16); s2d += __shfl_xor(s2d, 32);
                double dd1 = ee64g[l*KCODE + c1c] - 2.0*s1;
                double dd2 = ee64g[l*KCODE + c2c] - 2.0*s2d;
                if (dd2 < dd1 || (dd2 == dd1 && c2c < c1c)) bc = c2c;
            }
            // residual update: reference-exact fp32 op chain
            const float4* eb = (const float4*)(cb + ((size_t)l*KCODE + bc)*DIMV);
            #pragma unroll
            for (int st = 0; st < 4; ++st) {
                float4 a = eb[st*8 + q*2], b = eb[st*8 + q*2 + 1];
                float qv[8] = {a.x,a.y,a.z,a.w,b.x,b.y,b.z,b.w};
                #pragma unroll
                for (int j = 0; j < 8; ++j) {
                    float rv = r[mt][st][j];
                    float t1 = qv[j] - rv;              // z_q - residual
                    loss += (double)t1 * (double)t1;
                    float zqst = rv + t1;               // straight-through
                    r[mt][st][j] = rv - zqst;
                }
            }
            if (l < LEV - 1) {   // rebuild A-frags for next level
                #pragma unroll
                for (int st = 0; st < 4; ++st) {
                    f16x8 h, lo;
                    #pragma unroll
                    for (int j = 0; j < 8; ++j) {
                        float x = r[mt][st][j];
                        _Float16 hh = (_Float16)x;
                        h[j] = hh;
                        lo[j] = (_Float16)(x - (float)hh);
                    }
                    Ah[mt][st] = h; Al[mt][st] = lo;
                }
            } else {             // final output: z_q_total = z_e - residual_final
                const float4* zp = (const float4*)(ze + (size_t)(tokbase + mt*16 + col)*DIMV);
                float4* op = (float4*)(out + (size_t)(tokbase + mt*16 + col)*DIMV);
                #pragma unroll
                for (int st = 0; st < 4; ++st) {
                    float4 za = zp[st*8 + q*2], zb = zp[st*8 + q*2 + 1];
                    float4 oa, ob;
                    oa.x = za.x - r[mt][st][0]; oa.y = za.y - r[mt][st][1];
                    oa.z = za.z - r[mt][st][2]; oa.w = za.w - r[mt][st][3];
                    ob.x = zb.x - r[mt][st][4]; ob.y = zb.y - r[mt][st][5];
                    ob.z = zb.z - r[mt][st][6]; ob.w = zb.w - r[mt][st][7];
                    op[st*8 + q*2] = oa; op[st*8 + q*2 + 1] = ob;
                }
            }
            if (q == 0) out_idx[(size_t)(tokbase + mt*16 + col)*3 + l] = (float)bc;
        }
    }

    #pragma unroll
    for (int d = 1; d <= 32; d <<= 1) loss += __shfl_xor(loss, d);
    if ((tid & 63) == 0) ssum[wid] = loss;
    __syncthreads();
    if (tid == 0) atomicAdd(ws, ssum[0] + ssum[1] + ssum[2] + ssum[3]);
}

__global__ void rvq_fin(const double* __restrict__ ws, float* __restrict__ out) {
    double vq = ws[0] / ((double)N_TOK * (double)DIMV * (double)LEV);
    out[(size_t)N_TOK * DIMV + 0] = (float)vq;
    out[(size_t)N_TOK * DIMV + 1] = (float)(0.25 * vq);
}

extern "C" void kernel_launch(void* const* d_in, const int* in_sizes, int n_in,
                              void* d_out, int out_size, void* d_ws, size_t ws_size,
                              hipStream_t stream) {
    const float* ze = (const float*)d_in[0];
    const float* cb = (const float*)d_in[1];
    float* out = (float*)d_out;
    double* ws = (double*)d_ws;

    rvq_prep<<<(LEV * KCODE + 255) / 256, 256, 0, stream>>>(cb, ws);
    rvq_main<<<N_TOK / 128, BLOCK, 0, stream>>>(ze, cb, out, ws);
    rvq_fin<<<1, 1, 0, stream>>>(ws, out);
}